// Round 7
// baseline (132.593 us; speedup 1.0000x reference)
//
#include <hip/hip_runtime.h>
#include <stdint.h>

// Croston's method: B=8192 series x T=2048 steps. out = Z'/V' per step.
//
// Round 18: algorithmic restructure -- per-wave PARALLEL ASSOCIATIVE SCAN.
// R10-R17 exonerated staging mechanism, wave count, vmcnt discipline and
// store type: every variant pinned at 41-45us / ~2.7 TB/s while linear
// fills hit 6.3 TB/s. The only shared component left was the access SHAPE
// (8KB-strided 128B chunks + LDS transpose + per-wave serial chains).
// The Croston step is affine in the state for fixed x_t:
//   Z' = az*Z + bz              (az,bz) = nz ? (1-a, a*x) : (1, 0)
//   V' = p*V + r*q + s          nz: (1-a, a, 0)   z: (1, 0, 0)
//   q' = f*q + g                nz: (0, 1)        z: (1, 1)
// These maps compose (upper-triangular), so the T=2048 scan splits into
// 64 lane-local 32-step folds + a 6-round __shfl_up compose scan + a
// 32-step replay from registers. One wave = one series row:
//   - reads/writes are single-pass contiguous (lane = 128B of an 8KB row)
//   - NO LDS, NO transpose, NO warmup approximation (method is EXACT)
//   - traffic = true minimum 64MB read + 64MB write
//   - 8192 waves (32/CU in 2 rounds at launch_bounds(256,4)) = real TLP.
// Numerics: az/p products underflow toward 0 over long series (0.9^1365)
// -- harmless, that's genuine contraction; bz/s carry the value. f,g are
// small integers (exact in f32). Composition reassociates the same
// multiplies (error ~1 ulp per tree level, ~1e-6 rel << 0.0078 tol).

#define TLEN 2048

typedef float vf4 __attribute__((ext_vector_type(4)));

__global__ __launch_bounds__(256, 4) void croston_kernel(
    const float* __restrict__ x,
    const float* __restrict__ alpha,
    const float* __restrict__ Z0,
    const float* __restrict__ V0,
    const float* __restrict__ q0,
    float* __restrict__ out)
{
    const int lane = threadIdx.x & 63;
    const int wid  = blockIdx.x * 4 + (threadIdx.x >> 6);   // series id, 0..8191

    const float a  = alpha[0];
    const float ma = 1.0f - a;

    // Lane l owns time window [32l, 32l+32) of series `wid`.
    const float* row = x + (size_t)wid * TLEN + lane * 32;
    vf4 xv[8];
#pragma unroll
    for (int j = 0; j < 8; ++j)
        xv[j] = *(const vf4*)(row + j * 4);

    // ---- lane-local fold: compose 32 per-step affine maps ----
    float az = 1.f, bz = 0.f;           // Z' = az*Z + bz
    float p  = 1.f, r = 0.f, s = 0.f;   // V' = p*V + r*q + s
    float f  = 1.f, g = 0.f;            // q' = f*q + g
#pragma unroll
    for (int j = 0; j < 8; ++j) {
#pragma unroll
        for (int k = 0; k < 4; ++k) {
            const float xt = xv[j][k];
            const bool  nz = (xt != 0.f);
            // candidates for the nz case (use OLD f,g in r,s updates)
            const float az_n = ma * az;
            const float bz_n = fmaf(ma, bz, a * xt);
            const float p_n  = ma * p;
            const float r_n  = fmaf(ma, r, a * f);
            const float s_n  = fmaf(ma, s, a * g);
            az = nz ? az_n : az;
            bz = nz ? bz_n : bz;
            p  = nz ? p_n  : p;
            r  = nz ? r_n  : r;
            s  = nz ? s_n  : s;
            g  = nz ? 1.f  : (g + 1.f);  // g before f (r_n,s_n already took old g,f)
            f  = nz ? 0.f  : f;
        }
    }

    // ---- inclusive Hillis-Steele scan across 64 lanes (compose: cur o earlier) ----
#pragma unroll
    for (int d = 1; d < 64; d <<= 1) {
        const float az_o = __shfl_up(az, d);
        const float bz_o = __shfl_up(bz, d);
        const float p_o  = __shfl_up(p,  d);
        const float r_o  = __shfl_up(r,  d);
        const float s_o  = __shfl_up(s,  d);
        const float f_o  = __shfl_up(f,  d);
        const float g_o  = __shfl_up(g,  d);
        if (lane >= d) {
            // order matters: each line uses pre-update values of its inputs
            bz = fmaf(az, bz_o, bz);
            az = az * az_o;
            s  = fmaf(p, s_o, fmaf(r, g_o, s));
            r  = fmaf(p, r_o, r * f_o);
            p  = p * p_o;
            g  = fmaf(f, g_o, g);
            f  = f * f_o;
        }
    }

    // ---- exclusive prefix (shift one lane; identity at lane 0) ----
    float azE = __shfl_up(az, 1), bzE = __shfl_up(bz, 1);
    float pE  = __shfl_up(p, 1),  rE  = __shfl_up(r, 1), sE = __shfl_up(s, 1);
    float fE  = __shfl_up(f, 1),  gE  = __shfl_up(g, 1);
    if (lane == 0) {
        azE = 1.f; bzE = 0.f;
        pE  = 1.f; rE  = 0.f; sE = 0.f;
        fE  = 1.f; gE  = 0.f;
    }

    // ---- state at this lane's window start (exact) ----
    const float z0  = Z0[wid];
    const float v0  = V0[wid];
    const float qq0 = q0[wid];
    float Z = fmaf(azE, z0, bzE);
    float V = fmaf(pE, v0, fmaf(rE, qq0, sE));
    float q = fmaf(fE, qq0, gE);

    // ---- replay 32 steps from registers, emit out = Z'/V' ----
#pragma unroll
    for (int j = 0; j < 8; ++j) {
#pragma unroll
        for (int k = 0; k < 4; ++k) {
            const float xt = xv[j][k];
            const bool  nz = (xt != 0.f);
            const float Zn = fmaf(ma, Z, a * xt);
            const float Vn = fmaf(ma, V, a * q);
            Z = nz ? Zn : Z;
            V = nz ? Vn : V;
            q = nz ? 1.f : (q + 1.f);
            xv[j][k] = Z * __builtin_amdgcn_rcpf(V);
        }
    }

    float* orow = out + (size_t)wid * TLEN + lane * 32;
#pragma unroll
    for (int j = 0; j < 8; ++j)
        *(vf4*)(orow + j * 4) = xv[j];
}

extern "C" void kernel_launch(void* const* d_in, const int* in_sizes, int n_in,
                              void* d_out, int out_size, void* d_ws, size_t ws_size,
                              hipStream_t stream) {
    const float* x     = (const float*)d_in[0];
    const float* alpha = (const float*)d_in[1];
    const float* Z0    = (const float*)d_in[2];
    const float* V0    = (const float*)d_in[3];
    const float* q0    = (const float*)d_in[4];
    float* out = (float*)d_out;

    // 8192 waves = one per series; 256-thread blocks (4 series each).
    dim3 block(256);
    dim3 grid(2048);
    croston_kernel<<<grid, block, 0, stream>>>(x, alpha, Z0, V0, q0, out);
}

// Round 8
// 118.848 us; speedup vs baseline: 1.1157x; 1.1157x over previous
//
#include <hip/hip_runtime.h>
#include <stdint.h>

// Croston's method: B=8192 series x T=2048 steps. out = Z'/V' per step.
//
// Round 19 = R18's per-wave associative scan + ONE change: all global
// accesses are made fill-shaped (contiguous 1KB per instruction) via a
// swizzled, wave-private LDS transpose.
// R18 counters: 43us, 2.4 TB/s, FETCH 35.7MB (reads L3-hit), WRITE 66MB,
// VALU 24%, 0 conflicts -- not BW/VALU/occupancy/conflict bound. R18's
// loads/stores were lane-strided 128B -> each vmem instruction touched 64
// DISTINCT cache lines (1024 line-transactions/wave); the vector-memory
// line path is the one resource that scales with lines-per-instruction,
// matching the otherwise-unexplainable 43us. Fills (6.3 TB/s, 41us) are
// the existence proof for coalesced instructions.
// Transpose design (per wave, 2048 floats = 8KB LDS, PRIVATE to the wave
// -> no __syncthreads; in-order DS pipe + compiler lgkmcnt suffice):
//   time-granule G=t/4 (16B). Owner lane l=G>>3, slot m=G&7.
//   phys granule  = (G & ~7) | (m ^ (l&7))  i.e.
//     write (load inst j, lane l): r=j*8+(l>>3); e=(l&7)^((l>>3)&7);
//       W[r*32 + e*4] = 16B
//     read (lane l, slot m):  W[l*32 + ((m^(l&7))*4)]
//   Both phases hit 8 bank-quads x 8 lanes = the 8-cyc/KB LDS floor.
// Scan math unchanged from R18 (exact; no warmup; fold -> 6-round
// __shfl_up compose -> exclusive prefix -> replay).
// Occupancy: 32KB LDS/block(4 waves) -> 5 blocks/CU = 20 waves/CU.

#define TLEN 2048

typedef float vf4 __attribute__((ext_vector_type(4)));

__global__ __launch_bounds__(256) void croston_kernel(
    const float* __restrict__ x,
    const float* __restrict__ alpha,
    const float* __restrict__ Z0,
    const float* __restrict__ V0,
    const float* __restrict__ q0,
    float* __restrict__ out)
{
    __shared__ __attribute__((aligned(16))) float lds[4][2048]; // 8KB/wave

    const int warp = threadIdx.x >> 6;
    const int lane = threadIdx.x & 63;
    const int wid  = blockIdx.x * 4 + warp;   // series id, 0..8191
    float* W = lds[warp];                     // wave-private

    const float a  = alpha[0];
    const float ma = 1.0f - a;

    const int e  = (lane & 7) ^ ((lane >> 3) & 7);  // write-side swizzle
    const int l7 = lane & 7;                        // read-side swizzle key

    // ---- coalesced load (1KB contiguous per instruction) ----
    const float* row = x + (size_t)wid * TLEN;
    vf4 ld[8];
#pragma unroll
    for (int j = 0; j < 8; ++j)
        ld[j] = *(const vf4*)(row + j * 256 + lane * 4);

    // ---- swizzled scatter into LDS ----
#pragma unroll
    for (int j = 0; j < 8; ++j)
        *(vf4*)(W + (j * 8 + (lane >> 3)) * 32 + (e << 2)) = ld[j];

    // ---- swizzled gather: lane's 32-step window, time order ----
    vf4 xv[8];
#pragma unroll
    for (int m = 0; m < 8; ++m)
        xv[m] = *(const vf4*)(W + lane * 32 + ((m ^ l7) << 2));

    // ---- lane-local fold: compose 32 per-step affine maps ----
    float az = 1.f, bz = 0.f;           // Z' = az*Z + bz
    float p  = 1.f, r = 0.f, s = 0.f;   // V' = p*V + r*q + s
    float f  = 1.f, g = 0.f;            // q' = f*q + g
#pragma unroll
    for (int j = 0; j < 8; ++j) {
#pragma unroll
        for (int k = 0; k < 4; ++k) {
            const float xt = xv[j][k];
            const bool  nz = (xt != 0.f);
            const float az_n = ma * az;
            const float bz_n = fmaf(ma, bz, a * xt);
            const float p_n  = ma * p;
            const float r_n  = fmaf(ma, r, a * f);
            const float s_n  = fmaf(ma, s, a * g);
            az = nz ? az_n : az;
            bz = nz ? bz_n : bz;
            p  = nz ? p_n  : p;
            r  = nz ? r_n  : r;
            s  = nz ? s_n  : s;
            g  = nz ? 1.f  : (g + 1.f);  // g before f (r_n,s_n took old g,f)
            f  = nz ? 0.f  : f;
        }
    }

    // ---- inclusive Hillis-Steele scan across 64 lanes ----
#pragma unroll
    for (int d = 1; d < 64; d <<= 1) {
        const float az_o = __shfl_up(az, d);
        const float bz_o = __shfl_up(bz, d);
        const float p_o  = __shfl_up(p,  d);
        const float r_o  = __shfl_up(r,  d);
        const float s_o  = __shfl_up(s,  d);
        const float f_o  = __shfl_up(f,  d);
        const float g_o  = __shfl_up(g,  d);
        if (lane >= d) {
            bz = fmaf(az, bz_o, bz);
            az = az * az_o;
            s  = fmaf(p, s_o, fmaf(r, g_o, s));
            r  = fmaf(p, r_o, r * f_o);
            p  = p * p_o;
            g  = fmaf(f, g_o, g);
            f  = f * f_o;
        }
    }

    // ---- exclusive prefix (shift one lane; identity at lane 0) ----
    float azE = __shfl_up(az, 1), bzE = __shfl_up(bz, 1);
    float pE  = __shfl_up(p, 1),  rE  = __shfl_up(r, 1), sE = __shfl_up(s, 1);
    float fE  = __shfl_up(f, 1),  gE  = __shfl_up(g, 1);
    if (lane == 0) {
        azE = 1.f; bzE = 0.f;
        pE  = 1.f; rE  = 0.f; sE = 0.f;
        fE  = 1.f; gE  = 0.f;
    }

    // ---- state at this lane's window start (exact) ----
    const float z0  = Z0[wid];
    const float v0  = V0[wid];
    const float qq0 = q0[wid];
    float Z = fmaf(azE, z0, bzE);
    float V = fmaf(pE, v0, fmaf(rE, qq0, sE));
    float q = fmaf(fE, qq0, gE);

    // ---- replay 32 steps from registers, emit out = Z'/V' ----
#pragma unroll
    for (int j = 0; j < 8; ++j) {
#pragma unroll
        for (int k = 0; k < 4; ++k) {
            const float xt = xv[j][k];
            const bool  nz = (xt != 0.f);
            const float Zn = fmaf(ma, Z, a * xt);
            const float Vn = fmaf(ma, V, a * q);
            Z = nz ? Zn : Z;
            V = nz ? Vn : V;
            q = nz ? 1.f : (q + 1.f);
            xv[j][k] = Z * __builtin_amdgcn_rcpf(V);
        }
    }

    // ---- inverse transpose: swizzled scatter, coalesced gather+store ----
#pragma unroll
    for (int m = 0; m < 8; ++m)
        *(vf4*)(W + lane * 32 + ((m ^ l7) << 2)) = xv[m];

    float* orow = out + (size_t)wid * TLEN;
#pragma unroll
    for (int j = 0; j < 8; ++j) {
        vf4 o = *(const vf4*)(W + (j * 8 + (lane >> 3)) * 32 + (e << 2));
        *(vf4*)(orow + j * 256 + lane * 4) = o;
    }
}

extern "C" void kernel_launch(void* const* d_in, const int* in_sizes, int n_in,
                              void* d_out, int out_size, void* d_ws, size_t ws_size,
                              hipStream_t stream) {
    const float* x     = (const float*)d_in[0];
    const float* alpha = (const float*)d_in[1];
    const float* Z0    = (const float*)d_in[2];
    const float* V0    = (const float*)d_in[3];
    const float* q0    = (const float*)d_in[4];
    float* out = (float*)d_out;

    // 8192 waves = one per series; 256-thread blocks (4 series each).
    dim3 block(256);
    dim3 grid(2048);
    croston_kernel<<<grid, block, 0, stream>>>(x, alpha, Z0, V0, q0, out);
}

// Round 9
// 118.624 us; speedup vs baseline: 1.1178x; 1.0019x over previous
//
#include <hip/hip_runtime.h>
#include <stdint.h>

// Croston's method: B=8192 series x T=2048 steps. out = Z'/V' per step.
//
// Round 20: two-half pipelined scan + 4KB/wave LDS -> 32 waves/CU.
// R19 (coalesced vmem + swizzled transpose) was the first real win
// (bench 126->119, croston ~33us). Remaining gap vs the ~16-20us traffic
// floor: strict per-wave phase serialization (load->transpose->scan->
// store, no intra-wave overlap) + occupancy capped at 20 waves/CU by the
// 8KB/wave buffer. Fix:
//  - Split the series into two sequential 1024-step scans. EXACT: state
//    at t=1024 = lane63's inclusive map applied to the initial state
//    (broadcast via __shfl before the exclusive shift).
//  - 4KB/wave transpose buffer -> 16KB/block -> 32 waves/CU (TLP +60%).
//  - Pipeline: H2 global loads issue right after H1's LDS gather and fly
//    under H1 fold+scan+replay; H1 stores drain under H2 compute.
//  - Dropped scan param p: p == az identically (Z and V share the same
//    per-step decay nz?1-a:1), saving fold/scan/shuffle work that pays
//    for the extra 6-round scan.
// 4KB layout (per half, 1024 floats, 32-float rows): granule G=t/4 (16B),
// owner lane lo=G>>2, slot m=G&3, row=lo>>1, halfbit=lo&1;
// phys quad = ((halfbit<<2)|m) ^ (row&7); addr = row*32 + quad*4.
// Hand-checked: loads (j,l): rows j*8+(l>>3), every lane-octet covers all
// 8 quads; lane reads row l>>1: quads ((l&1)<<2|m)^((l>>1)&7), all 8 per
// octet -> every wave64 b128 phase is at the structural 8-cyc floor.

#define TLEN 2048
#define HALF 1024

typedef float vf4 __attribute__((ext_vector_type(4)));

__global__ __launch_bounds__(256) void croston_kernel(
    const float* __restrict__ x,
    const float* __restrict__ alpha,
    const float* __restrict__ Z0,
    const float* __restrict__ V0,
    const float* __restrict__ q0,
    float* __restrict__ out)
{
    __shared__ __attribute__((aligned(16))) float lds[4][HALF]; // 4KB/wave

    const int warp = threadIdx.x >> 6;
    const int lane = threadIdx.x & 63;
    const int wid  = blockIdx.x * 4 + warp;   // series id, 0..8191
    float* W = lds[warp];                     // wave-private

    const float a  = alpha[0];
    const float ma = 1.0f - a;

    // granule-side (load/store) transpose address: inst j adds j*8 rows
    const int rg  = lane >> 3;                               // row-in-inst
    const int pqg = ((((lane >> 2) & 1) << 2) | (lane & 3)) ^ ((lane >> 3) & 7);
    const int goff = rg * 32 + pqg * 4;                      // + j*256

    // lane-side (scan window) transpose address: slot m
    const int rowl = lane >> 1;
    const int lbase = rowl * 32;
    const int lkey  = rowl & 7;
    const int lhalf = (lane & 1) << 2;

    auto lane_off = [&](int m) { return lbase + (((lhalf | m) ^ lkey) << 2); };

    // ---- associative scan over one 1024-step half ----
    // On entry: xv[m] = lane's 16-step window (time order), (Zs,Vs,qs) =
    // exact series state at the half's start. On exit: xv[m] = outputs,
    // (Zs,Vs,qs) = exact state at the half's end.
    auto scan_half = [&](vf4* xv, float& Zs, float& Vs, float& qs) {
        // fold: compose 16 per-step affine maps (p dropped: p == az)
        float az = 1.f, bz = 0.f, r = 0.f, s = 0.f, f = 1.f, g = 0.f;
#pragma unroll
        for (int m = 0; m < 4; ++m) {
#pragma unroll
            for (int k = 0; k < 4; ++k) {
                const float xt = xv[m][k];
                const bool  nz = (xt != 0.f);
                const float az_n = ma * az;
                const float bz_n = fmaf(ma, bz, a * xt);
                const float r_n  = fmaf(ma, r, a * f);
                const float s_n  = fmaf(ma, s, a * g);
                az = nz ? az_n : az;
                bz = nz ? bz_n : bz;
                r  = nz ? r_n  : r;
                s  = nz ? s_n  : s;
                g  = nz ? 1.f  : (g + 1.f);   // r_n,s_n already took old f,g
                f  = nz ? 0.f  : f;
            }
        }
        // inclusive Hillis-Steele compose scan across 64 lanes
#pragma unroll
        for (int d = 1; d < 64; d <<= 1) {
            const float az_o = __shfl_up(az, d);
            const float bz_o = __shfl_up(bz, d);
            const float r_o  = __shfl_up(r,  d);
            const float s_o  = __shfl_up(s,  d);
            const float f_o  = __shfl_up(f,  d);
            const float g_o  = __shfl_up(g,  d);
            if (lane >= d) {
                bz = fmaf(az, bz_o, bz);
                s  = fmaf(az, s_o, fmaf(r, g_o, s));
                r  = fmaf(az, r_o, r * f_o);
                az = az * az_o;
                g  = fmaf(f, g_o, g);
                f  = f * f_o;
            }
        }
        // totals (lane 63 inclusive) -> exact state at half end
        const float azT = __shfl(az, 63), bzT = __shfl(bz, 63);
        const float rT  = __shfl(r, 63),  sT  = __shfl(s, 63);
        const float fT  = __shfl(f, 63),  gT  = __shfl(g, 63);
        const float Ze = fmaf(azT, Zs, bzT);
        const float Ve = fmaf(azT, Vs, fmaf(rT, qs, sT));
        const float qe = fmaf(fT, qs, gT);
        // exclusive prefix (shift one lane; identity at lane 0)
        float azE = __shfl_up(az, 1), bzE = __shfl_up(bz, 1);
        float rE  = __shfl_up(r, 1),  sE  = __shfl_up(s, 1);
        float fE  = __shfl_up(f, 1),  gE  = __shfl_up(g, 1);
        if (lane == 0) {
            azE = 1.f; bzE = 0.f; rE = 0.f; sE = 0.f; fE = 1.f; gE = 0.f;
        }
        // state at this lane's window start (exact)
        float Z = fmaf(azE, Zs, bzE);
        float V = fmaf(azE, Vs, fmaf(rE, qs, sE));
        float q = fmaf(fE, qs, gE);
        // replay 16 steps, emit out = Z'/V'
#pragma unroll
        for (int m = 0; m < 4; ++m) {
#pragma unroll
            for (int k = 0; k < 4; ++k) {
                const float xt = xv[m][k];
                const bool  nz = (xt != 0.f);
                const float Zn = fmaf(ma, Z, a * xt);
                const float Vn = fmaf(ma, V, a * q);
                Z = nz ? Zn : Z;
                V = nz ? Vn : V;
                q = nz ? 1.f : (q + 1.f);
                xv[m][k] = Z * __builtin_amdgcn_rcpf(V);
            }
        }
        Zs = Ze; Vs = Ve; qs = qe;
    };

    const float* row  = x   + (size_t)wid * TLEN;
    float*       orow = out + (size_t)wid * TLEN;

    float Zs = Z0[wid], Vs = V0[wid], qs = q0[wid];

    // ---- H1: load (coalesced 1KB/inst) -> transpose in ----
    vf4 ld[4];
#pragma unroll
    for (int j = 0; j < 4; ++j)
        ld[j] = *(const vf4*)(row + j * 256 + lane * 4);
#pragma unroll
    for (int j = 0; j < 4; ++j)
        *(vf4*)(W + j * 256 + goff) = ld[j];
    vf4 xv[4];
#pragma unroll
    for (int m = 0; m < 4; ++m)
        xv[m] = *(const vf4*)(W + lane_off(m));

    // ---- issue H2 loads now: they fly under H1 fold+scan+replay ----
#pragma unroll
    for (int j = 0; j < 4; ++j)
        ld[j] = *(const vf4*)(row + HALF + j * 256 + lane * 4);

    scan_half(xv, Zs, Vs, qs);

    // ---- H1 out: transpose out -> coalesced stores ----
#pragma unroll
    for (int m = 0; m < 4; ++m)
        *(vf4*)(W + lane_off(m)) = xv[m];
#pragma unroll
    for (int j = 0; j < 4; ++j) {
        const vf4 o = *(const vf4*)(W + j * 256 + goff);
        *(vf4*)(orow + j * 256 + lane * 4) = o;
    }

    // ---- H2: transpose in (WAR on W ordered by in-order DS pipe) ----
#pragma unroll
    for (int j = 0; j < 4; ++j)
        *(vf4*)(W + j * 256 + goff) = ld[j];
#pragma unroll
    for (int m = 0; m < 4; ++m)
        xv[m] = *(const vf4*)(W + lane_off(m));

    scan_half(xv, Zs, Vs, qs);

    // ---- H2 out ----
#pragma unroll
    for (int m = 0; m < 4; ++m)
        *(vf4*)(W + lane_off(m)) = xv[m];
#pragma unroll
    for (int j = 0; j < 4; ++j) {
        const vf4 o = *(const vf4*)(W + j * 256 + goff);
        *(vf4*)(orow + HALF + j * 256 + lane * 4) = o;
    }
}

extern "C" void kernel_launch(void* const* d_in, const int* in_sizes, int n_in,
                              void* d_out, int out_size, void* d_ws, size_t ws_size,
                              hipStream_t stream) {
    const float* x     = (const float*)d_in[0];
    const float* alpha = (const float*)d_in[1];
    const float* Z0    = (const float*)d_in[2];
    const float* V0    = (const float*)d_in[3];
    const float* q0    = (const float*)d_in[4];
    float* out = (float*)d_out;

    // 8192 waves = one per series; 256-thread blocks (4 series each).
    // 16KB LDS/block -> 32 waves/CU if VGPR <= 64 (watch VGPR_Count).
    dim3 block(256);
    dim3 grid(2048);
    croston_kernel<<<grid, block, 0, stream>>>(x, alpha, Z0, V0, q0, out);
}